// Round 14
// baseline (397.994 us; speedup 1.0000x reference)
//
#include <hip/hip_runtime.h>
#include <hip/hip_bf16.h>

#define B_ 64
#define H1_ 64
#define W1_ 32
#define Hp 70
#define Wp 35
#define C_ 128
#define NH_ 4
#define HD_ 32
#define WS_ 7
#define SS_ 3
#define NWC_ 5
#define NWIN_ 50
#define NTOK_ 49
#define SCALE_ 0.17677669529663687f

typedef __hip_bfloat16 bf16;
typedef __attribute__((ext_vector_type(8))) short sh8;     // 8 bf16 = 4 VGPR
typedef __attribute__((ext_vector_type(4))) float f32x4;   // MFMA acc

__device__ __forceinline__ float bs2f(short s) {
    unsigned int u = ((unsigned int)(unsigned short)s) << 16;
    float f; __builtin_memcpy(&f, &u, 4); return f;
}
__device__ __forceinline__ short f2bs(float f) {
    bf16 h = __float2bfloat16(f);
    return *reinterpret_cast<short*>(&h);
}

// ---- prep: fp32 weights -> bf16 [N][K] + precomputed attn-bias table ----
// ws layout (shorts): wq[384][128] @0 ; wp[128][128] @49152 ; w1[512][128] @65536 ;
//                     w2[128][512] @131072 ; bt[4][64][64] @196608 ;
//                     x1b bf16[64*2048*128] @212992 (if ws_size permits)
__global__ void prep_k(const float* __restrict__ qkvw, const float* __restrict__ projw,
                       const float* __restrict__ f1w, const float* __restrict__ f2w,
                       const float* __restrict__ rpb,
                       short* __restrict__ ws) {
    int tid = blockIdx.x * 256 + threadIdx.x;          // 832*256 = 212992 total
    if (tid < 49152) {
        int n = tid >> 7, k = tid & 127;               // qkv_w [128][384]
        ws[tid] = f2bs(qkvw[k*384 + n]);
    } else if (tid < 65536) {
        int t = tid - 49152; int n = t >> 7, k = t & 127;   // proj_w [128][128]
        ws[tid] = f2bs(projw[k*128 + n]);
    } else if (tid < 131072) {
        int t = tid - 65536; int n = t >> 7, k = t & 127;   // fc1_w [128][512]
        ws[tid] = f2bs(f1w[k*512 + n]);
    } else if (tid < 196608) {
        int t = tid - 131072; int n = t >> 9, k = t & 511;  // fc2_w [512][128]
        ws[tid] = f2bs(f2w[k*128 + n]);
    } else if (tid < 212992) {
        int t = tid - 196608;                               // bt [4][64][64]
        int h = t >> 12, i = (t >> 6) & 63, j = t & 63;
        float val = -30000.f;                               // padded rows/cols
        if (i < NTOK_ && j < NTOK_) {
            int ri = i / WS_, ci = i % WS_, rj = j / WS_, cj = j % WS_;
            val = rpb[((ri - rj + 6)*13 + (ci - cj + 6))*4 + h];
        }
        ws[tid] = f2bs(val);
    }
}

// ---- win_attn, 8 waves (r13 structure); residual -> bf16 ws (or fp32 out) ----
__global__ __launch_bounds__(512, 4) void win_attn(
    const float* __restrict__ x,
    const float* __restrict__ n1g, const float* __restrict__ n1b,
    const float* __restrict__ qkvb, const short* __restrict__ bt,
    const float* __restrict__ projb,
    const short* __restrict__ wq, const short* __restrict__ wp,
    short* __restrict__ x1b, int use_ws,
    float* __restrict__ out)
{
    __shared__ char smem[71680];
    short* q_s = (short*)smem;
    short* k_s = (short*)(smem + 17408);
    short* cat = (short*)(smem + 17408);
    short* vt  = (short*)(smem + 34816);
    short* xsp = (short*)(smem + 53248);
    short* p_s = (short*)(smem + 53248);

    const int tid = threadIdx.x;
    const int lane = tid & 63, wv = tid >> 6;
    const int l15 = lane & 15, l4 = lane >> 4;
    const int mt = wv & 3, hg = wv >> 2;
    const int bw = blockIdx.x;
    const int b = bw / NWIN_, win = bw % NWIN_;
    const int wr = win / NWC_, wc = win % NWC_;

    // ---- phase A1: gather + LN1, float4; 2 rows/wave/iter ----
    #pragma unroll
    for (int it = 0; it < 4; ++it) {
        int n = it*16 + wv*2 + (lane >> 5);
        int r = n / WS_, cc = n % WS_;
        int h = (wr*WS_ + r + SS_) % Hp;
        int w = (wc*WS_ + cc + SS_) % Wp;
        int c0 = (lane & 31) * 4;
        float4 v = make_float4(0.f, 0.f, 0.f, 0.f);
        if (n < NTOK_ && h < H1_ && w < W1_)
            v = *(const float4*)(x + ((size_t)(b*H1_*W1_ + h*W1_ + w))*C_ + c0);
        float s  = v.x + v.y + v.z + v.w;
        float sq = v.x*v.x + v.y*v.y + v.z*v.z + v.w*v.w;
        #pragma unroll
        for (int off = 1; off < 32; off <<= 1) {
            s  += __shfl_xor(s, off);
            sq += __shfl_xor(sq, off);
        }
        float mean = s * (1.f/128.f);
        float var  = sq * (1.f/128.f) - mean*mean;   // biased var (jnp.var)
        float rstd = rsqrtf(var + 1e-5f);
        short4 o;
        o.x = f2bs((v.x - mean)*rstd*n1g[c0+0] + n1b[c0+0]);
        o.y = f2bs((v.y - mean)*rstd*n1g[c0+1] + n1b[c0+1]);
        o.z = f2bs((v.z - mean)*rstd*n1g[c0+2] + n1b[c0+2]);
        o.w = f2bs((v.w - mean)*rstd*n1g[c0+3] + n1b[c0+3]);
        *(short4*)(xsp + n*136 + c0) = o;
    }
    __syncthreads();

    // ---- phase A2: qkv, wave = 3 n-tiles x 4 m-tiles x K=128 ----
    {
        sh8 bq[4], bqn[4];
        {
            int n0 = (wv*3)*16 + l15;
            #pragma unroll
            for (int kk = 0; kk < 4; ++kk)
                bq[kk] = *(const sh8*)(wq + n0*C_ + kk*32 + l4*8);
        }
        for (int t = 0; t < 3; ++t) {
            int n0 = (wv*3 + t)*16 + l15;
            if (t < 2) {
                int n1 = n0 + 16;
                #pragma unroll
                for (int kk = 0; kk < 4; ++kk)
                    bqn[kk] = *(const sh8*)(wq + n1*C_ + kk*32 + l4*8);
            }
            int mat = n0 >> 7, c = n0 & 127;
            float bias = qkvb[n0];
            float scl = (mat == 0) ? SCALE_ : 1.f;
            #pragma unroll
            for (int mt4 = 0; mt4 < 4; ++mt4) {
                f32x4 acc = {0.f,0.f,0.f,0.f};
                #pragma unroll
                for (int kk = 0; kk < 4; ++kk) {
                    sh8 av = *(const sh8*)(xsp + (mt4*16 + l15)*136 + kk*32 + l4*8);
                    acc = __builtin_amdgcn_mfma_f32_16x16x32_bf16(av, bq[kk], acc, 0,0,0);
                }
                #pragma unroll
                for (int r = 0; r < 4; ++r) {
                    int m0 = mt4*16 + l4*4 + r;
                    float vc = (acc[r] + bias) * scl;
                    if (mat == 0)      q_s[m0*136 + c] = f2bs(vc);
                    else if (mat == 1) k_s[m0*136 + c] = f2bs(vc);
                    else               vt[c*72 + m0]   = f2bs(vc);
                }
            }
            #pragma unroll
            for (int kk = 0; kk < 4; ++kk) bq[kk] = bqn[kk];
        }
    }
    __syncthreads();

    // ---- phase B: attention; wave = (mt, heads hg*2..hg*2+1) ----
    int zi_r[4];
    #pragma unroll
    for (int r = 0; r < 4; ++r) {
        int i = mt*16 + l4*4 + r;
        int ri = i / WS_, ci = i % WS_;
        int hi = wr*WS_ + ri, wi = wc*WS_ + ci;
        zi_r[r] = (hi < 63 ? 0 : (hi < 67 ? 1 : 2))*3 + (wi < 28 ? 0 : (wi < 32 ? 1 : 2));
    }
    int zj_n[4];
    #pragma unroll
    for (int nt = 0; nt < 4; ++nt) {
        int j = nt*16 + l15;
        int rj = j / WS_, cj = j % WS_;
        int hj = wr*WS_ + rj, wj = wc*WS_ + cj;
        zj_n[nt] = (hj < 63 ? 0 : (hj < 67 ? 1 : 2))*3 + (wj < 28 ? 0 : (wj < 32 ? 1 : 2));
    }

    short* myp = p_s + wv*16*72;     // per-wave P slice
    f32x4 o_acc[2][2] = {};
    #pragma unroll
    for (int hl = 0; hl < 2; ++hl) {
        const int h = hg*2 + hl;
        sh8 aq = *(const sh8*)(q_s + (mt*16 + l15)*136 + h*HD_ + l4*8);
        f32x4 s[4];
        __builtin_amdgcn_s_setprio(1);
        #pragma unroll
        for (int nt = 0; nt < 4; ++nt) {
            sh8 bk = *(const sh8*)(k_s + (nt*16 + l15)*136 + h*HD_ + l4*8);
            f32x4 z = {0.f,0.f,0.f,0.f};
            s[nt] = __builtin_amdgcn_mfma_f32_16x16x32_bf16(aq, bk, z, 0,0,0);
        }
        __builtin_amdgcn_s_setprio(0);
        #pragma unroll
        for (int r = 0; r < 4; ++r) {
            const short* btrow = bt + ((size_t)(h*64 + mt*16 + l4*4 + r))*64 + l15;
            #pragma unroll
            for (int nt = 0; nt < 4; ++nt) {
                float sv = s[nt][r] + bs2f(btrow[nt*16]);
                if (zi_r[r] != zj_n[nt]) sv -= 100.f;
                s[nt][r] = sv;
            }
        }
        #pragma unroll
        for (int r = 0; r < 4; ++r) {
            float m0 = fmaxf(fmaxf(s[0][r], s[1][r]), fmaxf(s[2][r], s[3][r]));
            #pragma unroll
            for (int off = 1; off < 16; off <<= 1) m0 = fmaxf(m0, __shfl_xor(m0, off));
            float ls = 0.f;
            #pragma unroll
            for (int nt = 0; nt < 4; ++nt) {
                float e = __expf(s[nt][r] - m0);
                s[nt][r] = e; ls += e;
            }
            #pragma unroll
            for (int off = 1; off < 16; off <<= 1) ls += __shfl_xor(ls, off);
            float inv = 1.f / ls;
            #pragma unroll
            for (int nt = 0; nt < 4; ++nt)
                myp[(l4*4 + r)*72 + nt*16 + l15] = f2bs(s[nt][r] * inv);
        }
        sh8 ap0 = *(const sh8*)(myp + l15*72 + l4*8);
        sh8 ap1 = *(const sh8*)(myp + l15*72 + 32 + l4*8);
        __builtin_amdgcn_s_setprio(1);
        #pragma unroll
        for (int nt2 = 0; nt2 < 2; ++nt2) {
            sh8 bv0 = *(const sh8*)(vt + (h*HD_ + nt2*16 + l15)*72 + l4*8);
            sh8 bv1 = *(const sh8*)(vt + (h*HD_ + nt2*16 + l15)*72 + 32 + l4*8);
            o_acc[hl][nt2] = __builtin_amdgcn_mfma_f32_16x16x32_bf16(ap0, bv0, o_acc[hl][nt2], 0,0,0);
            o_acc[hl][nt2] = __builtin_amdgcn_mfma_f32_16x16x32_bf16(ap1, bv1, o_acc[hl][nt2], 0,0,0);
        }
        __builtin_amdgcn_s_setprio(0);
    }

    __syncthreads();   // k_s reads done -> cat may overlay

    // ---- phase C: cat (own rows) -> proj -> residual store ----
    #pragma unroll
    for (int hl = 0; hl < 2; ++hl)
        #pragma unroll
        for (int nt2 = 0; nt2 < 2; ++nt2)
            #pragma unroll
            for (int r = 0; r < 4; ++r)
                cat[(mt*16 + l4*4 + r)*136 + (hg*2+hl)*HD_ + nt2*16 + l15] = f2bs(o_acc[hl][nt2][r]);

    bool pred[4]; size_t tokb[4];
    #pragma unroll
    for (int r = 0; r < 4; ++r) {
        int m = mt*16 + l4*4 + r;
        int rr = m / WS_, cc = m % WS_;
        int hh = (wr*WS_ + rr + SS_) % Hp;
        int ww = (wc*WS_ + cc + SS_) % Wp;
        pred[r] = (m < NTOK_) && (hh < H1_) && (ww < W1_);
        tokb[r] = ((size_t)(b*H1_*W1_ + hh*W1_ + ww))*C_;
    }

    sh8 pa[4];
    #pragma unroll
    for (int kk = 0; kk < 4; ++kk)
        pa[kk] = *(const sh8*)(cat + (mt*16 + l15)*136 + kk*32 + l4*8);

    sh8 bpw[4], bpwn[4];
    #pragma unroll
    for (int kk = 0; kk < 4; ++kk)
        bpw[kk] = *(const sh8*)(wp + (hg*64 + l15)*C_ + kk*32 + l4*8);
    for (int nt = 0; nt < 4; ++nt) {
        int ch = hg*64 + nt*16 + l15;
        if (nt < 3) {
            #pragma unroll
            for (int kk = 0; kk < 4; ++kk)
                bpwn[kk] = *(const sh8*)(wp + (ch+16)*C_ + kk*32 + l4*8);
        }
        f32x4 acc = {0.f,0.f,0.f,0.f};
        #pragma unroll
        for (int kk = 0; kk < 4; ++kk)
            acc = __builtin_amdgcn_mfma_f32_16x16x32_bf16(pa[kk], bpw[kk], acc, 0,0,0);
        float pbv = projb[ch];
        if (use_ws) {
            #pragma unroll
            for (int r = 0; r < 4; ++r)
                if (pred[r])
                    x1b[tokb[r] + ch] = f2bs(x[tokb[r] + ch] + acc[r] + pbv);
        } else {
            #pragma unroll
            for (int r = 0; r < 4; ++r)
                if (pred[r])
                    out[tokb[r] + ch] = x[tokb[r] + ch] + acc[r] + pbv;
        }
        #pragma unroll
        for (int kk = 0; kk < 4; ++kk) bpw[kk] = bpwn[kk];
    }
}

// ---- mlp v5: reads bf16 residual from ws (or fp32 in-place fallback), ----
// ---- writes final fp32 to d_out exactly once (write-only d_out).       ----
// LDS: h2 bf16[64][136] @0 (17408) | hv bf16[64][264] @17408 (33792)
//      outs f32[64][132] @17408 (overlays dead hv)   -> total 51200, 3 blk/CU
__global__ __launch_bounds__(512, 6) void mlp_k(
    const short* __restrict__ x1b, int use_ws,
    float* __restrict__ xio,
    const float* __restrict__ n2g, const float* __restrict__ n2b,
    const float* __restrict__ f1b, const float* __restrict__ f2b,
    const short* __restrict__ w1, const short* __restrict__ w2)
{
    __shared__ char smem[51200];
    short* h2  = (short*)smem;               // [64][136]
    short* hv  = (short*)(smem + 17408);     // [64][264]
    float* outs= (float*)(smem + 17408);     // [64][132], after hv dies

    const int tid = threadIdx.x;
    const int lane = tid & 63, wv = tid >> 6;
    const int l15 = lane & 15, l4 = lane >> 4;
    const int mh = wv & 1, ng = wv >> 1;
    const size_t base = (size_t)blockIdx.x * 64 * C_;

    // ---- stage raw residual into h2 (bf16), cooperative full-line loads ----
    if (use_ws) {
        const sh8* src = (const sh8*)(x1b + base);
        for (int i = tid; i < 1024; i += 512) {
            sh8 v = src[i];
            int row = i >> 4, col = (i & 15) * 8;
            *(sh8*)(h2 + row*136 + col) = v;
        }
    } else {
        for (int i = tid; i < 2048; i += 512) {
            float4 v = ((const float4*)(xio + base))[i];
            int row = i >> 5, col = (i & 31) * 4;
            short4 o;
            o.x = f2bs(v.x); o.y = f2bs(v.y); o.z = f2bs(v.z); o.w = f2bs(v.w);
            *(short4*)(h2 + row*136 + col) = o;
        }
    }
    __syncthreads();

    // ---- read phase: LN2 inputs + residual fragment regs (before overwrite) ----
    int tok = tid >> 3, sub = tid & 7;
    float vbuf[16];
    float s = 0.f, sq = 0.f;
    #pragma unroll
    for (int c = 0; c < 16; ++c) {
        float v = bs2f(h2[tok*136 + sub*16 + c]);
        vbuf[c] = v; s += v; sq += v*v;
    }
    float res[2][2][4];
    #pragma unroll
    for (int mt2 = 0; mt2 < 2; ++mt2)
        #pragma unroll
        for (int nt = 0; nt < 2; ++nt)
            #pragma unroll
            for (int r = 0; r < 4; ++r) {
                int m  = (mh*2 + mt2)*16 + l4*4 + r;
                int ch = ng*32 + nt*16 + l15;
                res[mt2][nt][r] = bs2f(h2[m*136 + ch]);
            }
    #pragma unroll
    for (int off = 1; off < 8; off <<= 1) {
        s  += __shfl_xor(s, off);
        sq += __shfl_xor(sq, off);
    }
    float mean = s * (1.f/128.f);
    float var  = sq * (1.f/128.f) - mean*mean;
    float rstd = rsqrtf(var + 1e-5f);
    __syncthreads();   // all raw reads done -> safe to overwrite h2
    #pragma unroll
    for (int c = 0; c < 16; ++c) {
        int ch = sub*16 + c;
        h2[tok*136 + ch] = f2bs((vbuf[c] - mean)*rstd*n2g[ch] + n2b[ch]);
    }
    __syncthreads();

    f32x4 facc[2][2] = {};
    #pragma unroll 1
    for (int chunk = 0; chunk < 2; ++chunk) {
        const int c0 = chunk*256;
        // ---- fc1 + GELU: chunk-local cols ng*64..+63, both m-tiles ----
        {
            sh8 b1[4], b1n[4];
            #pragma unroll
            for (int kk = 0; kk < 4; ++kk)
                b1[kk] = *(const sh8*)(w1 + (size_t)(c0 + ng*64 + l15)*C_ + kk*32 + l4*8);
            for (int t = 0; t < 4; ++t) {
                int n = c0 + ng*64 + t*16 + l15;
                if (t < 3) {
                    #pragma unroll
                    for (int kk = 0; kk < 4; ++kk)
                        b1n[kk] = *(const sh8*)(w1 + (size_t)(n + 16)*C_ + kk*32 + l4*8);
                }
                float bias = f1b[n];
                #pragma unroll
                for (int mt2 = 0; mt2 < 2; ++mt2) {
                    int mrow = (mh*2 + mt2)*16;
                    f32x4 acc = {0.f,0.f,0.f,0.f};
                    #pragma unroll
                    for (int kk = 0; kk < 4; ++kk) {
                        sh8 av = *(const sh8*)(h2 + (mrow + l15)*136 + kk*32 + l4*8);
                        acc = __builtin_amdgcn_mfma_f32_16x16x32_bf16(av, b1[kk], acc, 0,0,0);
                    }
                    #pragma unroll
                    for (int r = 0; r < 4; ++r) {
                        float xv = acc[r] + bias;
                        float g = xv * 0.5f * (1.f + erff(xv * 0.70710678118654752f));
                        hv[(mrow + l4*4 + r)*264 + ng*64 + t*16 + l15] = f2bs(g);
                    }
                }
                #pragma unroll
                for (int kk = 0; kk < 4; ++kk) b1[kk] = b1n[kk];
            }
        }
        __syncthreads();
        // ---- fc2 partial: K = [c0, c0+256), out cols ng*32..+31, both m-tiles ----
        {
            sh8 b2[2], b2n[2];
            #pragma unroll
            for (int nt = 0; nt < 2; ++nt)
                b2[nt] = *(const sh8*)(w2 + (size_t)(ng*32 + nt*16 + l15)*512 + c0 + l4*8);
            for (int ks = 0; ks < 8; ++ks) {
                if (ks < 7) {
                    #pragma unroll
                    for (int nt = 0; nt < 2; ++nt)
                        b2n[nt] = *(const sh8*)(w2 + (size_t)(ng*32 + nt*16 + l15)*512 + c0 + (ks+1)*32 + l4*8);
                }
                #pragma unroll
                for (int mt2 = 0; mt2 < 2; ++mt2) {
                    sh8 av = *(const sh8*)(hv + ((mh*2 + mt2)*16 + l15)*264 + ks*32 + l4*8);
                    facc[mt2][0] = __builtin_amdgcn_mfma_f32_16x16x32_bf16(av, b2[0], facc[mt2][0], 0,0,0);
                    facc[mt2][1] = __builtin_amdgcn_mfma_f32_16x16x32_bf16(av, b2[1], facc[mt2][1], 0,0,0);
                }
                b2[0] = b2n[0]; b2[1] = b2n[1];
            }
        }
        __syncthreads();   // chunk 0: hv rewritten; chunk 1: hv -> outs overlay
    }

    // ---- epilogue: results -> LDS, cooperative full-line fp32 store ----
    #pragma unroll
    for (int mt2 = 0; mt2 < 2; ++mt2)
        #pragma unroll
        for (int nt = 0; nt < 2; ++nt) {
            int oc = ng*32 + nt*16 + l15;
            float bias = f2b[oc];
            #pragma unroll
            for (int r = 0; r < 4; ++r) {
                int m = (mh*2 + mt2)*16 + l4*4 + r;
                outs[m*132 + oc] = res[mt2][nt][r] + facc[mt2][nt][r] + bias;
            }
        }
    __syncthreads();
    for (int i = tid; i < 2048; i += 512) {
        int row = i >> 5, col = (i & 31) * 4;
        ((float4*)(xio + base))[i] = *(const float4*)(outs + row*132 + col);
    }
}

extern "C" void kernel_launch(void* const* d_in, const int* in_sizes, int n_in,
                              void* d_out, int out_size, void* d_ws, size_t ws_size,
                              hipStream_t stream) {
    const float* x    = (const float*)d_in[0];
    const float* n1g  = (const float*)d_in[1];
    const float* n1b  = (const float*)d_in[2];
    const float* qkvw = (const float*)d_in[3];
    const float* qkvb = (const float*)d_in[4];
    const float* rpb  = (const float*)d_in[5];
    const float* pw   = (const float*)d_in[6];
    const float* pb   = (const float*)d_in[7];
    const float* n2g  = (const float*)d_in[8];
    const float* n2b  = (const float*)d_in[9];
    const float* f1w  = (const float*)d_in[10];
    const float* f1b  = (const float*)d_in[11];
    const float* f2w  = (const float*)d_in[12];
    const float* f2b  = (const float*)d_in[13];

    short* ws = (short*)d_ws;          // bf16 weights + bias table + x1b
    const short* wq = ws;
    const short* wp = ws + 49152;
    const short* w1 = ws + 65536;
    const short* w2 = ws + 131072;
    const short* bt = ws + 196608;
    short* x1b = ws + 212992;
    // need: (212992 + 64*2048*128) shorts = 33,980,416 bytes
    const size_t need = (size_t)(212992 + 64*2048*128) * 2;
    const int use_ws = (ws_size >= need) ? 1 : 0;
    float* xio = (float*)d_out;

    hipLaunchKernelGGL(prep_k, dim3(832), dim3(256), 0, stream, qkvw, pw, f1w, f2w, rpb, ws);
    hipLaunchKernelGGL(win_attn, dim3(B_*NWIN_), dim3(512), 0, stream,
                       x, n1g, n1b, qkvb, bt, pb, wq, wp, x1b, use_ws, xio);
    hipLaunchKernelGGL(mlp_k, dim3(B_*H1_*W1_/64), dim3(512), 0, stream,
                       x1b, use_ws, xio, n2g, n2b, f1b, f2b, w1, w2);
}

// Round 15
// 307.531 us; speedup vs baseline: 1.2942x; 1.2942x over previous
//
#include <hip/hip_runtime.h>
#include <hip/hip_bf16.h>

#define B_ 64
#define H1_ 64
#define W1_ 32
#define Hp 70
#define Wp 35
#define C_ 128
#define NH_ 4
#define HD_ 32
#define WS_ 7
#define SS_ 3
#define NWC_ 5
#define NWIN_ 50
#define NTOK_ 49
#define SCALE_ 0.17677669529663687f

typedef __hip_bfloat16 bf16;
typedef __attribute__((ext_vector_type(8))) short sh8;     // 8 bf16 = 4 VGPR
typedef __attribute__((ext_vector_type(4))) float f32x4;   // MFMA acc

__device__ __forceinline__ float bs2f(short s) {
    unsigned int u = ((unsigned int)(unsigned short)s) << 16;
    float f; __builtin_memcpy(&f, &u, 4); return f;
}
__device__ __forceinline__ short f2bs(float f) {
    bf16 h = __float2bfloat16(f);
    return *reinterpret_cast<short*>(&h);
}

// ---- prep: fp32 weights -> bf16 [N][K] + precomputed attn-bias table ----
// ws layout (shorts): wq[384][128] @0 ; wp[128][128] @49152 ; w1[512][128] @65536 ;
//                     w2[128][512] @131072 ; bt[4][64][64] @196608 (ends 212992)
__global__ void prep_k(const float* __restrict__ qkvw, const float* __restrict__ projw,
                       const float* __restrict__ f1w, const float* __restrict__ f2w,
                       const float* __restrict__ rpb,
                       short* __restrict__ ws) {
    int tid = blockIdx.x * 256 + threadIdx.x;          // 832*256 = 212992 total
    if (tid < 49152) {
        int n = tid >> 7, k = tid & 127;               // qkv_w [128][384]
        ws[tid] = f2bs(qkvw[k*384 + n]);
    } else if (tid < 65536) {
        int t = tid - 49152; int n = t >> 7, k = t & 127;   // proj_w [128][128]
        ws[tid] = f2bs(projw[k*128 + n]);
    } else if (tid < 131072) {
        int t = tid - 65536; int n = t >> 7, k = t & 127;   // fc1_w [128][512]
        ws[tid] = f2bs(f1w[k*512 + n]);
    } else if (tid < 196608) {
        int t = tid - 131072; int n = t >> 9, k = t & 511;  // fc2_w [512][128]
        ws[tid] = f2bs(f2w[k*128 + n]);
    } else if (tid < 212992) {
        int t = tid - 196608;                               // bt [4][64][64]
        int h = t >> 12, i = (t >> 6) & 63, j = t & 63;
        float val = -30000.f;                               // padded rows/cols
        if (i < NTOK_ && j < NTOK_) {
            int ri = i / WS_, ci = i % WS_, rj = j / WS_, cj = j % WS_;
            val = rpb[((ri - rj + 6)*13 + (ci - cj + 6))*4 + h];
        }
        ws[tid] = f2bs(val);
    }
}

// ---- win_attn, 8 waves; float4 A1, bias-table phase B, 4 barriers (r13) ----
__global__ __launch_bounds__(512, 4) void win_attn(
    const float* __restrict__ x,
    const float* __restrict__ n1g, const float* __restrict__ n1b,
    const float* __restrict__ qkvb, const short* __restrict__ bt,
    const float* __restrict__ projb,
    const short* __restrict__ wq, const short* __restrict__ wp,
    float* __restrict__ out)
{
    __shared__ char smem[71680];
    short* q_s = (short*)smem;
    short* k_s = (short*)(smem + 17408);
    short* cat = (short*)(smem + 17408);
    short* vt  = (short*)(smem + 34816);
    short* xsp = (short*)(smem + 53248);
    short* p_s = (short*)(smem + 53248);

    const int tid = threadIdx.x;
    const int lane = tid & 63, wv = tid >> 6;
    const int l15 = lane & 15, l4 = lane >> 4;
    const int mt = wv & 3, hg = wv >> 2;
    const int bw = blockIdx.x;
    const int b = bw / NWIN_, win = bw % NWIN_;
    const int wr = win / NWC_, wc = win % NWC_;

    // ---- phase A1: gather + LN1, float4; 2 rows/wave/iter ----
    #pragma unroll
    for (int it = 0; it < 4; ++it) {
        int n = it*16 + wv*2 + (lane >> 5);
        int r = n / WS_, cc = n % WS_;
        int h = (wr*WS_ + r + SS_) % Hp;
        int w = (wc*WS_ + cc + SS_) % Wp;
        int c0 = (lane & 31) * 4;
        float4 v = make_float4(0.f, 0.f, 0.f, 0.f);
        if (n < NTOK_ && h < H1_ && w < W1_)
            v = *(const float4*)(x + ((size_t)(b*H1_*W1_ + h*W1_ + w))*C_ + c0);
        float s  = v.x + v.y + v.z + v.w;
        float sq = v.x*v.x + v.y*v.y + v.z*v.z + v.w*v.w;
        #pragma unroll
        for (int off = 1; off < 32; off <<= 1) {
            s  += __shfl_xor(s, off);
            sq += __shfl_xor(sq, off);
        }
        float mean = s * (1.f/128.f);
        float var  = sq * (1.f/128.f) - mean*mean;   // biased var (jnp.var)
        float rstd = rsqrtf(var + 1e-5f);
        short4 o;
        o.x = f2bs((v.x - mean)*rstd*n1g[c0+0] + n1b[c0+0]);
        o.y = f2bs((v.y - mean)*rstd*n1g[c0+1] + n1b[c0+1]);
        o.z = f2bs((v.z - mean)*rstd*n1g[c0+2] + n1b[c0+2]);
        o.w = f2bs((v.w - mean)*rstd*n1g[c0+3] + n1b[c0+3]);
        *(short4*)(xsp + n*136 + c0) = o;
    }
    __syncthreads();

    // ---- phase A2: qkv, wave = 3 n-tiles x 4 m-tiles x K=128 ----
    {
        sh8 bq[4], bqn[4];
        {
            int n0 = (wv*3)*16 + l15;
            #pragma unroll
            for (int kk = 0; kk < 4; ++kk)
                bq[kk] = *(const sh8*)(wq + n0*C_ + kk*32 + l4*8);
        }
        for (int t = 0; t < 3; ++t) {
            int n0 = (wv*3 + t)*16 + l15;
            if (t < 2) {
                int n1 = n0 + 16;
                #pragma unroll
                for (int kk = 0; kk < 4; ++kk)
                    bqn[kk] = *(const sh8*)(wq + n1*C_ + kk*32 + l4*8);
            }
            int mat = n0 >> 7, c = n0 & 127;
            float bias = qkvb[n0];
            float scl = (mat == 0) ? SCALE_ : 1.f;
            #pragma unroll
            for (int mt4 = 0; mt4 < 4; ++mt4) {
                f32x4 acc = {0.f,0.f,0.f,0.f};
                #pragma unroll
                for (int kk = 0; kk < 4; ++kk) {
                    sh8 av = *(const sh8*)(xsp + (mt4*16 + l15)*136 + kk*32 + l4*8);
                    acc = __builtin_amdgcn_mfma_f32_16x16x32_bf16(av, bq[kk], acc, 0,0,0);
                }
                #pragma unroll
                for (int r = 0; r < 4; ++r) {
                    int m0 = mt4*16 + l4*4 + r;
                    float vc = (acc[r] + bias) * scl;
                    if (mat == 0)      q_s[m0*136 + c] = f2bs(vc);
                    else if (mat == 1) k_s[m0*136 + c] = f2bs(vc);
                    else               vt[c*72 + m0]   = f2bs(vc);
                }
            }
            #pragma unroll
            for (int kk = 0; kk < 4; ++kk) bq[kk] = bqn[kk];
        }
    }
    __syncthreads();

    // ---- phase B: attention; wave = (mt, heads hg*2..hg*2+1) ----
    int zi_r[4];
    #pragma unroll
    for (int r = 0; r < 4; ++r) {
        int i = mt*16 + l4*4 + r;
        int ri = i / WS_, ci = i % WS_;
        int hi = wr*WS_ + ri, wi = wc*WS_ + ci;
        zi_r[r] = (hi < 63 ? 0 : (hi < 67 ? 1 : 2))*3 + (wi < 28 ? 0 : (wi < 32 ? 1 : 2));
    }
    int zj_n[4];
    #pragma unroll
    for (int nt = 0; nt < 4; ++nt) {
        int j = nt*16 + l15;
        int rj = j / WS_, cj = j % WS_;
        int hj = wr*WS_ + rj, wj = wc*WS_ + cj;
        zj_n[nt] = (hj < 63 ? 0 : (hj < 67 ? 1 : 2))*3 + (wj < 28 ? 0 : (wj < 32 ? 1 : 2));
    }

    short* myp = p_s + wv*16*72;     // per-wave P slice
    f32x4 o_acc[2][2] = {};
    #pragma unroll
    for (int hl = 0; hl < 2; ++hl) {
        const int h = hg*2 + hl;
        sh8 aq = *(const sh8*)(q_s + (mt*16 + l15)*136 + h*HD_ + l4*8);
        f32x4 s[4];
        __builtin_amdgcn_s_setprio(1);
        #pragma unroll
        for (int nt = 0; nt < 4; ++nt) {
            sh8 bk = *(const sh8*)(k_s + (nt*16 + l15)*136 + h*HD_ + l4*8);
            f32x4 z = {0.f,0.f,0.f,0.f};
            s[nt] = __builtin_amdgcn_mfma_f32_16x16x32_bf16(aq, bk, z, 0,0,0);
        }
        __builtin_amdgcn_s_setprio(0);
        #pragma unroll
        for (int r = 0; r < 4; ++r) {
            const short* btrow = bt + ((size_t)(h*64 + mt*16 + l4*4 + r))*64 + l15;
            #pragma unroll
            for (int nt = 0; nt < 4; ++nt) {
                float sv = s[nt][r] + bs2f(btrow[nt*16]);
                if (zi_r[r] != zj_n[nt]) sv -= 100.f;
                s[nt][r] = sv;
            }
        }
        #pragma unroll
        for (int r = 0; r < 4; ++r) {
            float m0 = fmaxf(fmaxf(s[0][r], s[1][r]), fmaxf(s[2][r], s[3][r]));
            #pragma unroll
            for (int off = 1; off < 16; off <<= 1) m0 = fmaxf(m0, __shfl_xor(m0, off));
            float ls = 0.f;
            #pragma unroll
            for (int nt = 0; nt < 4; ++nt) {
                float e = __expf(s[nt][r] - m0);
                s[nt][r] = e; ls += e;
            }
            #pragma unroll
            for (int off = 1; off < 16; off <<= 1) ls += __shfl_xor(ls, off);
            float inv = 1.f / ls;
            #pragma unroll
            for (int nt = 0; nt < 4; ++nt)
                myp[(l4*4 + r)*72 + nt*16 + l15] = f2bs(s[nt][r] * inv);
        }
        sh8 ap0 = *(const sh8*)(myp + l15*72 + l4*8);
        sh8 ap1 = *(const sh8*)(myp + l15*72 + 32 + l4*8);
        __builtin_amdgcn_s_setprio(1);
        #pragma unroll
        for (int nt2 = 0; nt2 < 2; ++nt2) {
            sh8 bv0 = *(const sh8*)(vt + (h*HD_ + nt2*16 + l15)*72 + l4*8);
            sh8 bv1 = *(const sh8*)(vt + (h*HD_ + nt2*16 + l15)*72 + 32 + l4*8);
            o_acc[hl][nt2] = __builtin_amdgcn_mfma_f32_16x16x32_bf16(ap0, bv0, o_acc[hl][nt2], 0,0,0);
            o_acc[hl][nt2] = __builtin_amdgcn_mfma_f32_16x16x32_bf16(ap1, bv1, o_acc[hl][nt2], 0,0,0);
        }
        __builtin_amdgcn_s_setprio(0);
    }

    __syncthreads();   // k_s reads done -> cat may overlay

    // ---- phase C: cat (own rows; no cross-wave -> no barrier) -> proj -> scatter ----
    #pragma unroll
    for (int hl = 0; hl < 2; ++hl)
        #pragma unroll
        for (int nt2 = 0; nt2 < 2; ++nt2)
            #pragma unroll
            for (int r = 0; r < 4; ++r)
                cat[(mt*16 + l4*4 + r)*136 + (hg*2+hl)*HD_ + nt2*16 + l15] = f2bs(o_acc[hl][nt2][r]);

    bool pred[4]; size_t tokb[4];
    #pragma unroll
    for (int r = 0; r < 4; ++r) {
        int m = mt*16 + l4*4 + r;
        int rr = m / WS_, cc = m % WS_;
        int hh = (wr*WS_ + rr + SS_) % Hp;
        int ww = (wc*WS_ + cc + SS_) % Wp;
        pred[r] = (m < NTOK_) && (hh < H1_) && (ww < W1_);
        tokb[r] = ((size_t)(b*H1_*W1_ + hh*W1_ + ww))*C_;
    }

    sh8 pa[4];
    #pragma unroll
    for (int kk = 0; kk < 4; ++kk)
        pa[kk] = *(const sh8*)(cat + (mt*16 + l15)*136 + kk*32 + l4*8);

    sh8 bpw[4], bpwn[4];
    #pragma unroll
    for (int kk = 0; kk < 4; ++kk)
        bpw[kk] = *(const sh8*)(wp + (hg*64 + l15)*C_ + kk*32 + l4*8);
    for (int nt = 0; nt < 4; ++nt) {
        int ch = hg*64 + nt*16 + l15;
        if (nt < 3) {
            #pragma unroll
            for (int kk = 0; kk < 4; ++kk)
                bpwn[kk] = *(const sh8*)(wp + (ch+16)*C_ + kk*32 + l4*8);
        }
        f32x4 acc = {0.f,0.f,0.f,0.f};
        #pragma unroll
        for (int kk = 0; kk < 4; ++kk)
            acc = __builtin_amdgcn_mfma_f32_16x16x32_bf16(pa[kk], bpw[kk], acc, 0,0,0);
        float pbv = projb[ch];
        #pragma unroll
        for (int r = 0; r < 4; ++r)
            if (pred[r])
                out[tokb[r] + ch] = x[tokb[r] + ch] + acc[r] + pbv;
        #pragma unroll
        for (int kk = 0; kk < 4; ++kk) bpw[kk] = bpwn[kk];
    }
}

// ---- mlp v4 (r13 structure); launch bounds relaxed: NO 40-VGPR spill cap ----
// LDS: xin f32[64][132] @0 | hv bf16[64][264] @0 (overlay) | outs f32 @0 ;
//      h2 bf16[64][136] @33792 -> total 51200
__global__ __launch_bounds__(512) void mlp_k(
    float* __restrict__ xio,
    const float* __restrict__ n2g, const float* __restrict__ n2b,
    const float* __restrict__ f1b, const float* __restrict__ f2b,
    const short* __restrict__ w1, const short* __restrict__ w2)
{
    __shared__ char smem[51200];
    float* xin = (float*)smem;               // [64][132]
    short* hv  = (short*)smem;               // [64][264], after xin dies
    float* outs= (float*)smem;               // [64][132], after hv dies
    short* h2  = (short*)(smem + 33792);     // [64][136]

    const int tid = threadIdx.x;
    const int lane = tid & 63, wv = tid >> 6;
    const int l15 = lane & 15, l4 = lane >> 4;
    const int mh = wv & 1, ng = wv >> 1;
    const size_t base = (size_t)blockIdx.x * 64 * C_;

    for (int i = tid; i < 2048; i += 512) {
        float4 v = ((const float4*)(xio + base))[i];
        int row = i >> 5, col = (i & 31) * 4;
        *(float4*)(xin + row*132 + col) = v;
    }
    __syncthreads();

    {
        int tok = tid >> 3, sub = tid & 7;
        float vbuf[16];
        float s = 0.f, sq = 0.f;
        #pragma unroll
        for (int c = 0; c < 16; ++c) {
            float v = xin[tok*132 + sub*16 + c];
            vbuf[c] = v; s += v; sq += v*v;
        }
        #pragma unroll
        for (int off = 1; off < 8; off <<= 1) {
            s  += __shfl_xor(s, off);
            sq += __shfl_xor(sq, off);
        }
        float mean = s * (1.f/128.f);
        float var  = sq * (1.f/128.f) - mean*mean;
        float rstd = rsqrtf(var + 1e-5f);
        #pragma unroll
        for (int c = 0; c < 16; ++c) {
            int ch = sub*16 + c;
            h2[tok*136 + ch] = f2bs((vbuf[c] - mean)*rstd*n2g[ch] + n2b[ch]);
        }
    }
    float res[2][2][4];
    #pragma unroll
    for (int mt2 = 0; mt2 < 2; ++mt2)
        #pragma unroll
        for (int nt = 0; nt < 2; ++nt)
            #pragma unroll
            for (int r = 0; r < 4; ++r) {
                int m  = (mh*2 + mt2)*16 + l4*4 + r;
                int ch = ng*32 + nt*16 + l15;
                res[mt2][nt][r] = xin[m*132 + ch];
            }
    __syncthreads();   // xin dead -> hv may overlay

    f32x4 facc[2][2] = {};
    #pragma unroll 1
    for (int chunk = 0; chunk < 2; ++chunk) {
        const int c0 = chunk*256;
        // ---- fc1 + GELU: chunk-local cols ng*64..+63, both m-tiles ----
        {
            sh8 b1[4], b1n[4];
            #pragma unroll
            for (int kk = 0; kk < 4; ++kk)
                b1[kk] = *(const sh8*)(w1 + (size_t)(c0 + ng*64 + l15)*C_ + kk*32 + l4*8);
            for (int t = 0; t < 4; ++t) {
                int n = c0 + ng*64 + t*16 + l15;
                if (t < 3) {
                    #pragma unroll
                    for (int kk = 0; kk < 4; ++kk)
                        b1n[kk] = *(const sh8*)(w1 + (size_t)(n + 16)*C_ + kk*32 + l4*8);
                }
                float bias = f1b[n];
                #pragma unroll
                for (int mt2 = 0; mt2 < 2; ++mt2) {
                    int mrow = (mh*2 + mt2)*16;
                    f32x4 acc = {0.f,0.f,0.f,0.f};
                    #pragma unroll
                    for (int kk = 0; kk < 4; ++kk) {
                        sh8 av = *(const sh8*)(h2 + (mrow + l15)*136 + kk*32 + l4*8);
                        acc = __builtin_amdgcn_mfma_f32_16x16x32_bf16(av, b1[kk], acc, 0,0,0);
                    }
                    #pragma unroll
                    for (int r = 0; r < 4; ++r) {
                        float xv = acc[r] + bias;
                        float g = xv * 0.5f * (1.f + erff(xv * 0.70710678118654752f));
                        hv[(mrow + l4*4 + r)*264 + ng*64 + t*16 + l15] = f2bs(g);
                    }
                }
                #pragma unroll
                for (int kk = 0; kk < 4; ++kk) b1[kk] = b1n[kk];
            }
        }
        __syncthreads();
        // ---- fc2 partial: K = [c0, c0+256), out cols ng*32..+31, both m-tiles ----
        {
            sh8 b2[2], b2n[2];
            #pragma unroll
            for (int nt = 0; nt < 2; ++nt)
                b2[nt] = *(const sh8*)(w2 + (size_t)(ng*32 + nt*16 + l15)*512 + c0 + l4*8);
            for (int ks = 0; ks < 8; ++ks) {
                if (ks < 7) {
                    #pragma unroll
                    for (int nt = 0; nt < 2; ++nt)
                        b2n[nt] = *(const sh8*)(w2 + (size_t)(ng*32 + nt*16 + l15)*512 + c0 + (ks+1)*32 + l4*8);
                }
                #pragma unroll
                for (int mt2 = 0; mt2 < 2; ++mt2) {
                    sh8 av = *(const sh8*)(hv + ((mh*2 + mt2)*16 + l15)*264 + ks*32 + l4*8);
                    facc[mt2][0] = __builtin_amdgcn_mfma_f32_16x16x32_bf16(av, b2[0], facc[mt2][0], 0,0,0);
                    facc[mt2][1] = __builtin_amdgcn_mfma_f32_16x16x32_bf16(av, b2[1], facc[mt2][1], 0,0,0);
                }
                b2[0] = b2n[0]; b2[1] = b2n[1];
            }
        }
        __syncthreads();
    }

    #pragma unroll
    for (int mt2 = 0; mt2 < 2; ++mt2)
        #pragma unroll
        for (int nt = 0; nt < 2; ++nt) {
            int oc = ng*32 + nt*16 + l15;
            float bias = f2b[oc];
            #pragma unroll
            for (int r = 0; r < 4; ++r) {
                int m = (mh*2 + mt2)*16 + l4*4 + r;
                outs[m*132 + oc] = res[mt2][nt][r] + facc[mt2][nt][r] + bias;
            }
        }
    __syncthreads();
    for (int i = tid; i < 2048; i += 512) {
        int row = i >> 5, col = (i & 31) * 4;
        ((float4*)(xio + base))[i] = *(const float4*)(outs + row*132 + col);
    }
}

extern "C" void kernel_launch(void* const* d_in, const int* in_sizes, int n_in,
                              void* d_out, int out_size, void* d_ws, size_t ws_size,
                              hipStream_t stream) {
    const float* x    = (const float*)d_in[0];
    const float* n1g  = (const float*)d_in[1];
    const float* n1b  = (const float*)d_in[2];
    const float* qkvw = (const float*)d_in[3];
    const float* qkvb = (const float*)d_in[4];
    const float* rpb  = (const float*)d_in[5];
    const float* pw   = (const float*)d_in[6];
    const float* pb   = (const float*)d_in[7];
    const float* n2g  = (const float*)d_in[8];
    const float* n2b  = (const float*)d_in[9];
    const float* f1w  = (const float*)d_in[10];
    const float* f1b  = (const float*)d_in[11];
    const float* f2w  = (const float*)d_in[12];
    const float* f2b  = (const float*)d_in[13];

    short* ws = (short*)d_ws;          // bf16 weights + bias table (426 KB)
    const short* wq = ws;
    const short* wp = ws + 49152;
    const short* w1 = ws + 65536;
    const short* w2 = ws + 131072;
    const short* bt = ws + 196608;
    float* xio = (float*)d_out;

    hipLaunchKernelGGL(prep_k, dim3(832), dim3(256), 0, stream, qkvw, pw, f1w, f2w, rpb, ws);
    hipLaunchKernelGGL(win_attn, dim3(B_*NWIN_), dim3(512), 0, stream,
                       x, n1g, n1b, qkvb, bt, pb, wq, wp, xio);
    hipLaunchKernelGGL(mlp_k, dim3(B_*H1_*W1_/64), dim3(512), 0, stream,
                       xio, n2g, n2b, f1b, f2b, w1, w2);
}